// Round 2
// baseline (555.603 us; speedup 1.0000x reference)
//
#include <hip/hip_runtime.h>
#include <stdint.h>

// ---------------------------------------------------------------------------
// VectorQuantizer: argmin_k ||x_n - c_k||^2 + straight-through out + losses.
//
// Token semantics (R4/R5/R7/R9-verified): candidates by continuous score
// s = ||c||^2 - 2 x.c via fp16 MFMA; exact fp64 re-score; token = lowest
// index within 0.75*ulp_fp32(Dmin) of the minimum.
//
// R9: packed-key epilogue -> gemm 197->129us. R10: scratch-free refine.
// R11: per-block LDS colmin (no global atomics).
// R12 FAILED: source-level register rotation was SSA-renamed away; WRITE
// 58->94MB (spill), dur unchanged. Diagnosis confirmed: 128 VGPR + 64 AGPR
// = 192/wave -> 2 waves/SIMD, all-direct global fragment loads, latency-
// bound (Mfma 11%, VALU 22%, HBM 14%, occ 21%).
// R13: m97-style K-loop. B-tile staged via global_load_lds into LDS
// (2 x 8KB slices of 128 codes x 32 dims, double-buffered, one barrier per
// K-step); A-fragments direct-to-reg with 1-step prefetch; next kt's first
// B-slice DMA overlaps the top-2 epilogue. [128][64B] LDS rows read at
// quad*16B are naturally conflict-free (8 bank-groups x 8 dwords) -- no
// swizzle needed. launch_bounds(256,3): ~160 combined regs -> 3 waves/SIMD.
// ---------------------------------------------------------------------------

#define N_ROWS 16384
#define DIM    256
#define KCODES 4096
#define NCHUNK 8
#define KC     (KCODES / NCHUNK)   // 512 codes per chunk
#define TM     128                 // rows per block tile
#define TN     128                 // codes per code-tile
#define BK     32                  // K per dc step
#define NKT    (KC / TN)           // 4 code tiles per chunk
#define NDC    (DIM / BK)          // 8 K-steps
#define NSTEP  (NKT * NDC)         // 32 pipeline steps
#define NGRAN  (NCHUNK * 2)        // 16 granules of 256 cols (chunk x chalf)
#define NRB    (N_ROWS / TM)       // 128 row-blocks

typedef float    f32x4 __attribute__((ext_vector_type(4)));
typedef _Float16 f16x8 __attribute__((ext_vector_type(8)));

#define GLOAD_LDS16(g, l) __builtin_amdgcn_global_load_lds(                 \
    (const __attribute__((address_space(1))) void*)(g),                     \
    (__attribute__((address_space(3))) void*)(l), 16, 0, 0)

__device__ __forceinline__ unsigned umin_(unsigned a, unsigned b) { return a < b ? a : b; }
__device__ __forceinline__ unsigned umax_(unsigned a, unsigned b) { return a > b ? a : b; }

// order-preserving float->uint key
__device__ __forceinline__ unsigned fkey(float f) {
    unsigned b = __float_as_uint(f);
    return (b & 0x80000000u) ? ~b : (b | 0x80000000u);
}
__device__ __forceinline__ float fkey_inv(unsigned k) {
    unsigned b = (k & 0x80000000u) ? (k ^ 0x80000000u) : ~k;
    return __uint_as_float(b);
}
__device__ __forceinline__ unsigned short f2h(float f) {
    union { _Float16 h; unsigned short u; } cv;
    cv.h = (_Float16)f;            // v_cvt_f16_f32, RNE
    return cv.u;
}

// sorted top-8 insert by (value, index) lexicographic
__device__ __forceinline__ void ins8(float w, int j, float v[8], int id[8]) {
    if (w < v[7] || (w == v[7] && j < id[7])) {
        v[7] = w; id[7] = j;
#pragma unroll
        for (int k = 7; k > 0; --k) {
            if (v[k] < v[k-1] || (v[k] == v[k-1] && id[k] < id[k-1])) {
                float tv = v[k]; v[k] = v[k-1]; v[k-1] = tv;
                int ti = id[k]; id[k] = id[k-1]; id[k-1] = ti;
            }
        }
    }
}

// ---- prep: fp16 cast + row sumsq (fp64->fp32) + buffer init, fused ----
__global__ __launch_bounds__(256) void vq_prep_kernel(
        const float* __restrict__ x, const float* __restrict__ cb,
        unsigned short* __restrict__ xh, unsigned short* __restrict__ ch,
        float* __restrict__ xsq, float* __restrict__ csq,
        unsigned* __restrict__ active, double* __restrict__ accum,
        unsigned* __restrict__ counter) {
    const int b = blockIdx.x, t = threadIdx.x;
    if (b < KCODES / 256) {
        int i = b * 256 + t;
        active[i] = 0u;
        if (i == 0) { accum[0] = 0.0; accum[1] = 0.0; counter[0] = 0u; }
    }
    const size_t NX = (size_t)N_ROWS * DIM;
    size_t e = (size_t)b * 1024 + (size_t)t * 4;
    const float* src; unsigned short* dst; float* sq; size_t off;
    if (e < NX) { src = x;  dst = xh; sq = xsq; off = e; }
    else        { src = cb; dst = ch; sq = csq; off = e - NX; }
    float4 v = *(const float4*)(src + off);
    ushort4 h;
    h.x = f2h(v.x); h.y = f2h(v.y); h.z = f2h(v.z); h.w = f2h(v.w);
    *(ushort4*)(dst + off) = h;
    double s = (double)v.x * v.x + (double)v.y * v.y
             + (double)v.z * v.z + (double)v.w * v.w;
    for (int o = 32; o; o >>= 1) s += __shfl_down(s, o);
    if ((t & 63) == 0) sq[off >> 8] = (float)s;
}

// ---- MFMA candidate GEMM, m97-style pipelined K-loop.
// grid = (NRB, NCHUNK), 256 thr (4 waves, 2x2 of 64x64 quadrants).
__global__ __launch_bounds__(256, 3) void vq_gemm_kernel(
        const unsigned short* __restrict__ xh_g, const unsigned short* __restrict__ ch_g,
        const float* __restrict__ xsq, const float* __restrict__ csq,
        unsigned* __restrict__ colmin_part, uint2* __restrict__ top2_out) {
    __shared__ __align__(16) unsigned short b_lds[2][TN][BK];  // 2 x 8 KB
    __shared__ float    xsq_l[128];
    __shared__ unsigned colmin_l[KC];

    const int t = threadIdx.x;
    const int wave = t >> 6, lane = t & 63, quad = lane >> 4, L = lane & 15;
    const int whalf = wave >> 1, chalf = wave & 1;
    const int row0  = blockIdx.x * TM;
    const int code0 = blockIdx.y * KC;

    if (t < 128) xsq_l[t] = xsq[row0 + t];
    colmin_l[t] = 0xFFFFFFFFu; colmin_l[t + 256] = 0xFFFFFFFFu;

    const unsigned short* abase =
        xh_g + ((size_t)(row0 + whalf * 64 + L) * DIM + quad * 8);

    // stage B slice (128 codes x 32 dims = 8KB) for (kt_,dc_) into buf.
    // 512 16B-chunks; chunk j: code = j>>2, 16B-col = j&3. Linear LDS dest
    // (wave-uniform base + lane*16 per global_load_lds semantics).
    const int j0 = wave * 64 + lane;
    auto stageB = [&](int buf, int kt_, int dc_) {
        const unsigned short* bsrc =
            ch_g + (size_t)(code0 + kt_ * TN) * DIM + dc_ * BK;
#pragma unroll
        for (int k = 0; k < 2; ++k) {
            const int j = j0 + k * 256;
            GLOAD_LDS16(bsrc + (size_t)(j >> 2) * DIM + (j & 3) * 8,
                        &b_lds[buf][j >> 2][(j & 3) * 8]);
        }
    };

    unsigned u1[16], u2[16];   // packed (quantized score | col9) running top-2
#pragma unroll
    for (int i = 0; i < 16; ++i) { u1[i] = 0xFFFFFFFFu; u2[i] = 0xFFFFFFFFu; }

    f16x8 af[2][4];
    float csq4[4];
    f32x4 acc[4][4];

    // prologue: first B slice DMA + first A fragment set
    stageB(0, 0, 0);
#pragma unroll
    for (int mt = 0; mt < 4; ++mt)
        af[0][mt] = *(const f16x8*)(abase + (size_t)mt * 16 * DIM);

#pragma unroll
    for (int s = 0; s < NSTEP; ++s) {
        const int kt = s >> 3, dc = s & 7, cur = s & 1;
        __syncthreads();           // buf[cur] staged; prev reads of cur^1 done

        if (dc == 0) {
#pragma unroll
            for (int nt = 0; nt < 4; ++nt) {
                csq4[nt] = csq[code0 + kt * TN + chalf * 64 + nt * 16 + L];
#pragma unroll
                for (int mt = 0; mt < 4; ++mt)
                    acc[mt][nt] = (f32x4){0.f, 0.f, 0.f, 0.f};
            }
        }

        if (s < NSTEP - 1) {
            const int sn = s + 1;
            stageB(cur ^ 1, sn >> 3, sn & 7);       // DMA next slice
#pragma unroll
            for (int mt = 0; mt < 4; ++mt)           // prefetch next A frags
                af[cur ^ 1][mt] = *(const f16x8*)(abase + (size_t)mt * 16 * DIM
                                                  + (sn & 7) * BK);
        }

        f16x8 bf[4];
#pragma unroll
        for (int nt = 0; nt < 4; ++nt)
            bf[nt] = *(const f16x8*)&b_lds[cur][chalf * 64 + nt * 16 + L][quad * 8];

#pragma unroll
        for (int mt = 0; mt < 4; ++mt)
#pragma unroll
            for (int nt = 0; nt < 4; ++nt)
                acc[mt][nt] = __builtin_amdgcn_mfma_f32_16x16x32_f16(
                    af[cur][mt], bf[nt], acc[mt][nt], 0, 0, 0);

        if (dc == 7) {
            // ---- epilogue: packed-key top-2 upkeep + column-min (LDS).
            // Overlaps the already-issued DMA of next kt's first slice.
            float dmin[4] = {3.4e38f, 3.4e38f, 3.4e38f, 3.4e38f};
#pragma unroll
            for (int mt = 0; mt < 4; ++mt) {
                const f32x4 xq = *(const f32x4*)&xsq_l[whalf * 64 + mt * 16 + quad * 4];
#pragma unroll
                for (int reg = 0; reg < 4; ++reg) {
                    const int i = mt * 4 + reg;
#pragma unroll
                    for (int nt = 0; nt < 4; ++nt) {
                        float sc = fmaf(-2.0f, acc[mt][nt][reg], csq4[nt]);
                        unsigned key = (fkey(sc) & 0xFFFFFE00u)
                                     | (unsigned)(kt * TN + chalf * 64 + nt * 16 + L);
                        unsigned lo = umin_(u1[i], key);
                        u2[i] = umin_(u2[i], umax_(u1[i], key));
                        u1[i] = lo;
                        dmin[nt] = fminf(dmin[nt], xq[reg] + sc);
                    }
                }
            }
#pragma unroll
            for (int nt = 0; nt < 4; ++nt) {
                unsigned dk = fkey(dmin[nt]);
                dk = umin_(dk, (unsigned)__shfl_xor((int)dk, 16));
                dk = umin_(dk, (unsigned)__shfl_xor((int)dk, 32));
                if (quad == 0)
                    atomicMin(&colmin_l[kt * TN + chalf * 64 + nt * 16 + L], dk);
            }
        }
    }

    // ---- once per block: butterfly-merge top-2 across the 16 L-lanes ----
#pragma unroll
    for (int i = 0; i < 16; ++i) {
#pragma unroll
        for (int st = 1; st < 16; st <<= 1) {
            unsigned w1 = (unsigned)__shfl_xor((int)u1[i], st);
            unsigned w2 = (unsigned)__shfl_xor((int)u2[i], st);
            unsigned a = umin_(u1[i], w1), b = umax_(u1[i], w1);
            u1[i] = a;
            u2[i] = umin_(umin_(u2[i], w2), b);
        }
    }
    if (L == 0) {
        const size_t gbase = (size_t)(blockIdx.y * 2 + chalf) * N_ROWS;
#pragma unroll
        for (int mt = 0; mt < 4; ++mt)
#pragma unroll
            for (int reg = 0; reg < 4; ++reg) {
                const int row = row0 + whalf * 64 + mt * 16 + quad * 4 + reg;
                top2_out[gbase + row] = make_uint2(u1[mt * 4 + reg], u2[mt * 4 + reg]);
            }
    }

    // ---- flush block-local colmin to private slice (plain stores) ----
    __syncthreads();
    unsigned* cp = colmin_part + (size_t)blockIdx.x * KCODES + code0;
    cp[t]       = colmin_l[t];
    cp[t + 256] = colmin_l[t + 256];
}

// ---- refine + gather + MSE, fused. grid = N_ROWS/4, 1 wave per row. ----
// Fast path: candidate gap > 1e-2 => winner certain, no fp64. Slow path:
// all 8 candidates, fully unrolled fp64 re-score, token = lowest index
// within 0.75*ulp_fp32(Dmin). No dynamic indexing (no scratch).
__global__ __launch_bounds__(256) void vq_refine_kernel(
        const float* __restrict__ x, const float* __restrict__ cb,
        const uint2* __restrict__ top2, unsigned* __restrict__ active,
        float* __restrict__ out, double* __restrict__ accum) {
    __shared__ double wsum[4];
    const int wave = threadIdx.x >> 6, lane = threadIdx.x & 63;
    const int row  = blockIdx.x * 4 + wave;

    float v[8]; int id[8];
#pragma unroll
    for (int k = 0; k < 8; ++k) { v[k] = 3.4e38f; id[k] = 0x7FFFFFFF; }
#pragma unroll
    for (int g = 0; g < NGRAN; ++g) {
        uint2 e = top2[(size_t)g * N_ROWS + row];
        const int cbase = (g >> 1) * KC;
        ins8(fkey_inv(e.x & 0xFFFFFE00u), cbase + (int)(e.x & 0x1FFu), v, id);
        ins8(fkey_inv(e.y & 0xFFFFFE00u), cbase + (int)(e.y & 0x1FFu), v, id);
    }

    float4 xv = ((const float4*)(x + (size_t)row * DIM))[lane];
    int tok;
    if (v[1] > v[0] + 1.0e-2f) {
        tok = id[0];
    } else {
        double xs64 = (double)xv.x * xv.x + (double)xv.y * xv.y
                    + (double)xv.z * xv.z + (double)xv.w * xv.w;
        double dd[8], cc2[8];
#pragma unroll
        for (int k = 0; k < 8; ++k) {
            float4 c4 = ((const float4*)(cb + (size_t)id[k] * DIM))[lane];
            dd[k]  = (double)xv.x * c4.x + (double)xv.y * c4.y
                   + (double)xv.z * c4.z + (double)xv.w * c4.w;
            cc2[k] = (double)c4.x * c4.x + (double)c4.y * c4.y
                   + (double)c4.z * c4.z + (double)c4.w * c4.w;
        }
#pragma unroll
        for (int o = 32; o; o >>= 1) {
            xs64 += __shfl_down(xs64, o);
#pragma unroll
            for (int k = 0; k < 8; ++k) {
                dd[k]  += __shfl_down(dd[k], o);
                cc2[k] += __shfl_down(cc2[k], o);
            }
        }
        if (lane == 0) {
            double D[8], Dmin = 1e300;
#pragma unroll
            for (int k = 0; k < 8; ++k) {
                D[k] = xs64 + cc2[k] - 2.0 * dd[k];
                Dmin = fmin(Dmin, D[k]);
            }
            int e2; frexp(Dmin, &e2);
            double U   = ldexp(1.0, e2 - 1 - 23);     // ulp_fp32(Dmin)
            double thr = Dmin + 0.75 * U;
            tok = 0x7FFFFFFF;
#pragma unroll
            for (int k = 0; k < 8; ++k)
                if (D[k] <= thr && id[k] < tok) tok = id[k];
        }
        tok = __shfl(tok, 0);
    }

    if (lane == 0) active[tok] = 1u;
    float4 sel = ((const float4*)(cb + (size_t)tok * DIM))[lane];
    ((float4*)out)[(size_t)row * 64 + lane] = sel;
    float dx = sel.x - xv.x, dy = sel.y - xv.y, dz = sel.z - xv.z, dw = sel.w - xv.w;
    float s = dx * dx + dy * dy + dz * dz + dw * dw;
    for (int o = 32; o; o >>= 1) s += __shfl_down(s, o);
    if (lane == 0) wsum[wave] = (double)s;
    __syncthreads();
    if (threadIdx.x == 0) atomicAdd(accum, wsum[0] + wsum[1] + wsum[2] + wsum[3]);
}

// ---- final: 128-way colmin reduction + entropy + loss. grid = 16 blocks.
// Each block reduces 256 codes over the 128 row-block partials, adds its
// inactive-code entropy partial; the 16th finisher computes the loss.
__global__ __launch_bounds__(256) void vq_final_kernel(
        const unsigned* __restrict__ colmin_part, const unsigned* __restrict__ active,
        double* __restrict__ accum, unsigned* __restrict__ counter,
        float* __restrict__ out) {
    __shared__ double red[256];
    const int t = threadIdx.x;
    const int c = blockIdx.x * 256 + t;
    unsigned m = 0xFFFFFFFFu;
#pragma unroll 8
    for (int rb = 0; rb < NRB; ++rb)
        m = umin_(m, colmin_part[(size_t)rb * KCODES + c]);
    red[t] = (active[c] == 0u) ? (double)fkey_inv(m) : 0.0;
    __syncthreads();
    for (int o = 128; o; o >>= 1) {
        if (t < o) red[t] += red[t + o];
        __syncthreads();
    }
    if (t == 0) {
        atomicAdd(&accum[1], red[0]);
        __threadfence();
        unsigned old = atomicAdd(counter, 1u);
        if (old == 15u) {
            __threadfence();
            double ent = atomicAdd(&accum[1], 0.0);   // atomic read
            double loss = 1.25 * (accum[0] / (double)((size_t)N_ROWS * DIM))
                        + 0.02 * (ent / (double)KCODES);
            out[(size_t)N_ROWS * DIM] = (float)loss;
        }
    }
}

extern "C" void kernel_launch(void* const* d_in, const int* in_sizes, int n_in,
                              void* d_out, int out_size, void* d_ws, size_t ws_size,
                              hipStream_t stream) {
    const float* x  = (const float*)d_in[0];   // [16384, 256]
    const float* cb = (const float*)d_in[1];   // [4096, 256]
    float* out = (float*)d_out;                // [16384*256] ++ [1] loss

    char* ws = (char*)d_ws;
    float*    xsq     = (float*)(ws + 0);                      // 64 KB
    float*    csq     = (float*)(ws + 65536);                  // 16 KB
    unsigned* active  = (unsigned*)(ws + 81920);               // 16 KB
    double*   accum   = (double*)(ws + 98304);                 // 256 B (mse, entropy)
    unsigned* counter = (unsigned*)(ws + 98560);               // 64 B
    uint2*    top2    = (uint2*)(ws + 131072);                 // 2 MB (16 granules)
    unsigned* cpart   = (unsigned*)(ws + 2228224);             // 2 MB (128 x 4096)
    unsigned short* xh_g = (unsigned short*)(ws + 4325376);    // 8 MB
    unsigned short* ch_g = (unsigned short*)(ws + 12713984);   // 2 MB (~14.2 MB)

    vq_prep_kernel<<<((N_ROWS + KCODES) * DIM) / 1024, 256, 0, stream>>>(
        x, cb, xh_g, ch_g, xsq, csq, active, accum, counter);
    vq_gemm_kernel<<<dim3(NRB, NCHUNK), 256, 0, stream>>>(
        xh_g, ch_g, xsq, csq, cpart, top2);
    vq_refine_kernel<<<N_ROWS / 4, 256, 0, stream>>>(
        x, cb, top2, active, out, accum);
    vq_final_kernel<<<KCODES / 256, 256, 0, stream>>>(
        cpart, active, accum, counter, out);
}

// Round 3
// 289.544 us; speedup vs baseline: 1.9189x; 1.9189x over previous
//
#include <hip/hip_runtime.h>
#include <stdint.h>

// ---------------------------------------------------------------------------
// VectorQuantizer: argmin_k ||x_n - c_k||^2 + straight-through out + losses.
//
// Token semantics (R4/R5/R7/R9-verified): candidates by continuous score
// s = ||c||^2 - 2 x.c via fp16 MFMA; exact fp64 re-score; token = lowest
// index within 0.75*ulp_fp32(Dmin) of the minimum.
//
// R9: packed-key epilogue. R10: scratch-free refine. R11: per-block LDS
// colmin (122us gemm, 270us total; latency-bound: 128VGPR+64AGPR=192 ->
// 2 waves/SIMD, ~54MB spill from u1/u2 + hoisted fragment cloud).
// R12 FAILED: source-level reg rotation SSA-renamed away (WRITE 94MB).
// R13 FAILED: LDS-staged B + launch_bounds(256,3) -> ACC spilled to
// scratch (84 VGPR, 880MB traffic, 3.4x slower) + 2M bank conflicts.
// R14: R11 base. Deterministic pressure cuts only:
//   (a) u1/u2 top-2 state -> LDS uint2[16][256] (32KB, conflict-free b64,
//       touched only in 4 epilogues) = hard -32 VGPR.
//   (b) #pragma unroll 2 on dc loop = bounded fragment in-flight (<=64
//       transient regs) instead of full-unroll 64-load cloud.
//   (c) xsq via LDS broadcast in epilogue (not 16 persistent regs).
// Est. ~95 VGPR + 64 AGPR ~= 160 combined -> 3 waves/SIMD at (256,3),
// with ~40 regs slack protecting the accumulators (R13 lesson).
// ---------------------------------------------------------------------------

#define N_ROWS 16384
#define DIM    256
#define KCODES 4096
#define NCHUNK 8
#define KC     (KCODES / NCHUNK)   // 512 codes per chunk
#define TM     128                 // rows per block tile
#define TN     128                 // codes per code-tile
#define BK     32                  // K per dc step
#define NKT    (KC / TN)           // 4 code tiles per chunk
#define NDC    (DIM / BK)          // 8 K-steps
#define NGRAN  (NCHUNK * 2)        // 16 granules of 256 cols (chunk x chalf)
#define NRB    (N_ROWS / TM)       // 128 row-blocks

typedef float    f32x4 __attribute__((ext_vector_type(4)));
typedef _Float16 f16x8 __attribute__((ext_vector_type(8)));

__device__ __forceinline__ unsigned umin_(unsigned a, unsigned b) { return a < b ? a : b; }
__device__ __forceinline__ unsigned umax_(unsigned a, unsigned b) { return a > b ? a : b; }

// order-preserving float->uint key
__device__ __forceinline__ unsigned fkey(float f) {
    unsigned b = __float_as_uint(f);
    return (b & 0x80000000u) ? ~b : (b | 0x80000000u);
}
__device__ __forceinline__ float fkey_inv(unsigned k) {
    unsigned b = (k & 0x80000000u) ? (k ^ 0x80000000u) : ~k;
    return __uint_as_float(b);
}
__device__ __forceinline__ unsigned short f2h(float f) {
    union { _Float16 h; unsigned short u; } cv;
    cv.h = (_Float16)f;            // v_cvt_f16_f32, RNE
    return cv.u;
}

// sorted top-8 insert by (value, index) lexicographic
__device__ __forceinline__ void ins8(float w, int j, float v[8], int id[8]) {
    if (w < v[7] || (w == v[7] && j < id[7])) {
        v[7] = w; id[7] = j;
#pragma unroll
        for (int k = 7; k > 0; --k) {
            if (v[k] < v[k-1] || (v[k] == v[k-1] && id[k] < id[k-1])) {
                float tv = v[k]; v[k] = v[k-1]; v[k-1] = tv;
                int ti = id[k]; id[k] = id[k-1]; id[k-1] = ti;
            }
        }
    }
}

// ---- prep: fp16 cast + row sumsq (fp64->fp32) + buffer init, fused ----
__global__ __launch_bounds__(256) void vq_prep_kernel(
        const float* __restrict__ x, const float* __restrict__ cb,
        unsigned short* __restrict__ xh, unsigned short* __restrict__ ch,
        float* __restrict__ xsq, float* __restrict__ csq,
        unsigned* __restrict__ active, double* __restrict__ accum,
        unsigned* __restrict__ counter) {
    const int b = blockIdx.x, t = threadIdx.x;
    if (b < KCODES / 256) {
        int i = b * 256 + t;
        active[i] = 0u;
        if (i == 0) { accum[0] = 0.0; accum[1] = 0.0; counter[0] = 0u; }
    }
    const size_t NX = (size_t)N_ROWS * DIM;
    size_t e = (size_t)b * 1024 + (size_t)t * 4;
    const float* src; unsigned short* dst; float* sq; size_t off;
    if (e < NX) { src = x;  dst = xh; sq = xsq; off = e; }
    else        { src = cb; dst = ch; sq = csq; off = e - NX; }
    float4 v = *(const float4*)(src + off);
    ushort4 h;
    h.x = f2h(v.x); h.y = f2h(v.y); h.z = f2h(v.z); h.w = f2h(v.w);
    *(ushort4*)(dst + off) = h;
    double s = (double)v.x * v.x + (double)v.y * v.y
             + (double)v.z * v.z + (double)v.w * v.w;
    for (int o = 32; o; o >>= 1) s += __shfl_down(s, o);
    if ((t & 63) == 0) sq[off >> 8] = (float)s;
}

// ---- MFMA candidate GEMM, barrier-free K-loop, packed-key epilogue.
// grid = (NRB, NCHUNK), 256 thr (4 waves, 2x2 of 64x64 quadrants).
__global__ __launch_bounds__(256, 3) void vq_gemm_kernel(
        const unsigned short* __restrict__ xh_g, const unsigned short* __restrict__ ch_g,
        const float* __restrict__ xsq, const float* __restrict__ csq,
        unsigned* __restrict__ colmin_part, uint2* __restrict__ top2_out) {
    __shared__ float    xsq_l[128];
    __shared__ unsigned colmin_l[KC];
    __shared__ uint2    u12_l[16][256];   // 32 KB: per-thread top-2 state

    const int t = threadIdx.x;
    const int wave = t >> 6, lane = t & 63, quad = lane >> 4, L = lane & 15;
    const int whalf = wave >> 1, chalf = wave & 1;
    const int row0  = blockIdx.x * TM;
    const int code0 = blockIdx.y * KC;

    if (t < 128) xsq_l[t] = xsq[row0 + t];
    colmin_l[t] = 0xFFFFFFFFu; colmin_l[t + 256] = 0xFFFFFFFFu;
#pragma unroll
    for (int i = 0; i < 16; ++i)
        u12_l[i][t] = make_uint2(0xFFFFFFFFu, 0xFFFFFFFFu);
    __syncthreads();

    const unsigned short* abase =
        xh_g + ((size_t)(row0 + whalf * 64 + L) * DIM + quad * 8);

    for (int kt = 0; kt < NKT; ++kt) {
        const int cb0 = code0 + kt * TN;
        const unsigned short* bbase =
            ch_g + ((size_t)(cb0 + chalf * 64 + L) * DIM + quad * 8);
        f32x4 acc[4][4];
#pragma unroll
        for (int mt = 0; mt < 4; ++mt)
#pragma unroll
            for (int nt = 0; nt < 4; ++nt) acc[mt][nt] = (f32x4){0.f, 0.f, 0.f, 0.f};

#pragma unroll 2
        for (int dc = 0; dc < NDC; ++dc) {
            f16x8 af[4], bf[4];
#pragma unroll
            for (int mt = 0; mt < 4; ++mt)
                af[mt] = *(const f16x8*)(abase + (size_t)mt * 16 * DIM + dc * BK);
#pragma unroll
            for (int nt = 0; nt < 4; ++nt)
                bf[nt] = *(const f16x8*)(bbase + (size_t)nt * 16 * DIM + dc * BK);
#pragma unroll
            for (int mt = 0; mt < 4; ++mt)
#pragma unroll
                for (int nt = 0; nt < 4; ++nt)
                    acc[mt][nt] = __builtin_amdgcn_mfma_f32_16x16x32_f16(
                        af[mt], bf[nt], acc[mt][nt], 0, 0, 0);
        }

        // ---- epilogue: packed-key top-2 upkeep (LDS state) + column-min ----
        float csq4[4]; unsigned colf[4];
        float dmin[4] = {3.4e38f, 3.4e38f, 3.4e38f, 3.4e38f};
#pragma unroll
        for (int nt = 0; nt < 4; ++nt) {
            csq4[nt] = csq[cb0 + chalf * 64 + nt * 16 + L];
            colf[nt] = (unsigned)(kt * 128 + chalf * 64 + nt * 16 + L);
        }
#pragma unroll
        for (int mt = 0; mt < 4; ++mt) {
            // broadcast read of 4 row-sumsq values (no persistent regs)
            const f32x4 xq = *(const f32x4*)&xsq_l[whalf * 64 + mt * 16 + quad * 4];
#pragma unroll
            for (int reg = 0; reg < 4; ++reg) {
                const int i = mt * 4 + reg;
                uint2 e = u12_l[i][t];
#pragma unroll
                for (int nt = 0; nt < 4; ++nt) {
                    float s = fmaf(-2.0f, acc[mt][nt][reg], csq4[nt]);
                    unsigned key = (fkey(s) & 0xFFFFFE00u) | colf[nt];
                    unsigned lo = umin_(e.x, key);
                    e.y = umin_(e.y, umax_(e.x, key));
                    e.x = lo;
                    dmin[nt] = fminf(dmin[nt], xq[reg] + s);
                }
                u12_l[i][t] = e;
            }
        }
#pragma unroll
        for (int nt = 0; nt < 4; ++nt) {
            unsigned dk = fkey(dmin[nt]);
            dk = umin_(dk, (unsigned)__shfl_xor((int)dk, 16));
            dk = umin_(dk, (unsigned)__shfl_xor((int)dk, 32));
            if (quad == 0)
                atomicMin(&colmin_l[kt * TN + chalf * 64 + nt * 16 + L], dk);
        }
    }

    // ---- once per block: butterfly-merge top-2 across the 16 L-lanes ----
    unsigned u1[16], u2[16];
#pragma unroll
    for (int i = 0; i < 16; ++i) {
        uint2 e = u12_l[i][t];
        u1[i] = e.x; u2[i] = e.y;
    }
#pragma unroll
    for (int i = 0; i < 16; ++i) {
#pragma unroll
        for (int st = 1; st < 16; st <<= 1) {
            unsigned w1 = (unsigned)__shfl_xor((int)u1[i], st);
            unsigned w2 = (unsigned)__shfl_xor((int)u2[i], st);
            unsigned a = umin_(u1[i], w1), b = umax_(u1[i], w1);
            u1[i] = a;
            u2[i] = umin_(umin_(u2[i], w2), b);
        }
    }
    if (L == 0) {
        const size_t gbase = (size_t)(blockIdx.y * 2 + chalf) * N_ROWS;
#pragma unroll
        for (int mt = 0; mt < 4; ++mt)
#pragma unroll
            for (int reg = 0; reg < 4; ++reg) {
                const int row = row0 + whalf * 64 + mt * 16 + quad * 4 + reg;
                top2_out[gbase + row] = make_uint2(u1[mt * 4 + reg], u2[mt * 4 + reg]);
            }
    }

    // ---- flush block-local colmin to private slice (plain stores) ----
    __syncthreads();
    unsigned* cp = colmin_part + (size_t)blockIdx.x * KCODES + code0;
    cp[t]       = colmin_l[t];
    cp[t + 256] = colmin_l[t + 256];
}

// ---- refine + gather + MSE, fused. grid = N_ROWS/4, 1 wave per row. ----
// Fast path: candidate gap > 1e-2 => winner certain, no fp64. Slow path:
// all 8 candidates, fully unrolled fp64 re-score, token = lowest index
// within 0.75*ulp_fp32(Dmin). No dynamic indexing (no scratch).
__global__ __launch_bounds__(256) void vq_refine_kernel(
        const float* __restrict__ x, const float* __restrict__ cb,
        const uint2* __restrict__ top2, unsigned* __restrict__ active,
        float* __restrict__ out, double* __restrict__ accum) {
    __shared__ double wsum[4];
    const int wave = threadIdx.x >> 6, lane = threadIdx.x & 63;
    const int row  = blockIdx.x * 4 + wave;

    float v[8]; int id[8];
#pragma unroll
    for (int k = 0; k < 8; ++k) { v[k] = 3.4e38f; id[k] = 0x7FFFFFFF; }
#pragma unroll
    for (int g = 0; g < NGRAN; ++g) {
        uint2 e = top2[(size_t)g * N_ROWS + row];
        const int cbase = (g >> 1) * KC;
        ins8(fkey_inv(e.x & 0xFFFFFE00u), cbase + (int)(e.x & 0x1FFu), v, id);
        ins8(fkey_inv(e.y & 0xFFFFFE00u), cbase + (int)(e.y & 0x1FFu), v, id);
    }

    float4 xv = ((const float4*)(x + (size_t)row * DIM))[lane];
    int tok;
    if (v[1] > v[0] + 1.0e-2f) {
        tok = id[0];
    } else {
        double xs64 = (double)xv.x * xv.x + (double)xv.y * xv.y
                    + (double)xv.z * xv.z + (double)xv.w * xv.w;
        double dd[8], cc2[8];
#pragma unroll
        for (int k = 0; k < 8; ++k) {
            float4 c4 = ((const float4*)(cb + (size_t)id[k] * DIM))[lane];
            dd[k]  = (double)xv.x * c4.x + (double)xv.y * c4.y
                   + (double)xv.z * c4.z + (double)xv.w * c4.w;
            cc2[k] = (double)c4.x * c4.x + (double)c4.y * c4.y
                   + (double)c4.z * c4.z + (double)c4.w * c4.w;
        }
#pragma unroll
        for (int o = 32; o; o >>= 1) {
            xs64 += __shfl_down(xs64, o);
#pragma unroll
            for (int k = 0; k < 8; ++k) {
                dd[k]  += __shfl_down(dd[k], o);
                cc2[k] += __shfl_down(cc2[k], o);
            }
        }
        if (lane == 0) {
            double D[8], Dmin = 1e300;
#pragma unroll
            for (int k = 0; k < 8; ++k) {
                D[k] = xs64 + cc2[k] - 2.0 * dd[k];
                Dmin = fmin(Dmin, D[k]);
            }
            int e2; frexp(Dmin, &e2);
            double U   = ldexp(1.0, e2 - 1 - 23);     // ulp_fp32(Dmin)
            double thr = Dmin + 0.75 * U;
            tok = 0x7FFFFFFF;
#pragma unroll
            for (int k = 0; k < 8; ++k)
                if (D[k] <= thr && id[k] < tok) tok = id[k];
        }
        tok = __shfl(tok, 0);
    }

    if (lane == 0) active[tok] = 1u;
    float4 sel = ((const float4*)(cb + (size_t)tok * DIM))[lane];
    ((float4*)out)[(size_t)row * 64 + lane] = sel;
    float dx = sel.x - xv.x, dy = sel.y - xv.y, dz = sel.z - xv.z, dw = sel.w - xv.w;
    float s = dx * dx + dy * dy + dz * dz + dw * dw;
    for (int o = 32; o; o >>= 1) s += __shfl_down(s, o);
    if (lane == 0) wsum[wave] = (double)s;
    __syncthreads();
    if (threadIdx.x == 0) atomicAdd(accum, wsum[0] + wsum[1] + wsum[2] + wsum[3]);
}

// ---- final: 128-way colmin reduction + entropy + loss. grid = 16 blocks.
// Each block reduces 256 codes over the 128 row-block partials, adds its
// inactive-code entropy partial; the 16th finisher computes the loss.
__global__ __launch_bounds__(256) void vq_final_kernel(
        const unsigned* __restrict__ colmin_part, const unsigned* __restrict__ active,
        double* __restrict__ accum, unsigned* __restrict__ counter,
        float* __restrict__ out) {
    __shared__ double red[256];
    const int t = threadIdx.x;
    const int c = blockIdx.x * 256 + t;
    unsigned m = 0xFFFFFFFFu;
#pragma unroll 8
    for (int rb = 0; rb < NRB; ++rb)
        m = umin_(m, colmin_part[(size_t)rb * KCODES + c]);
    red[t] = (active[c] == 0u) ? (double)fkey_inv(m) : 0.0;
    __syncthreads();
    for (int o = 128; o; o >>= 1) {
        if (t < o) red[t] += red[t + o];
        __syncthreads();
    }
    if (t == 0) {
        atomicAdd(&accum[1], red[0]);
        __threadfence();
        unsigned old = atomicAdd(counter, 1u);
        if (old == 15u) {
            __threadfence();
            double ent = atomicAdd(&accum[1], 0.0);   // atomic read
            double loss = 1.25 * (accum[0] / (double)((size_t)N_ROWS * DIM))
                        + 0.02 * (ent / (double)KCODES);
            out[(size_t)N_ROWS * DIM] = (float)loss;
        }
    }
}

extern "C" void kernel_launch(void* const* d_in, const int* in_sizes, int n_in,
                              void* d_out, int out_size, void* d_ws, size_t ws_size,
                              hipStream_t stream) {
    const float* x  = (const float*)d_in[0];   // [16384, 256]
    const float* cb = (const float*)d_in[1];   // [4096, 256]
    float* out = (float*)d_out;                // [16384*256] ++ [1] loss

    char* ws = (char*)d_ws;
    float*    xsq     = (float*)(ws + 0);                      // 64 KB
    float*    csq     = (float*)(ws + 65536);                  // 16 KB
    unsigned* active  = (unsigned*)(ws + 81920);               // 16 KB
    double*   accum   = (double*)(ws + 98304);                 // 256 B (mse, entropy)
    unsigned* counter = (unsigned*)(ws + 98560);               // 64 B
    uint2*    top2    = (uint2*)(ws + 131072);                 // 2 MB (16 granules)
    unsigned* cpart   = (unsigned*)(ws + 2228224);             // 2 MB (128 x 4096)
    unsigned short* xh_g = (unsigned short*)(ws + 4325376);    // 8 MB
    unsigned short* ch_g = (unsigned short*)(ws + 12713984);   // 2 MB (~14.2 MB)

    vq_prep_kernel<<<((N_ROWS + KCODES) * DIM) / 1024, 256, 0, stream>>>(
        x, cb, xh_g, ch_g, xsq, csq, active, accum, counter);
    vq_gemm_kernel<<<dim3(NRB, NCHUNK), 256, 0, stream>>>(
        xh_g, ch_g, xsq, csq, cpart, top2);
    vq_refine_kernel<<<N_ROWS / 4, 256, 0, stream>>>(
        x, cb, top2, active, out, accum);
    vq_final_kernel<<<KCODES / 256, 256, 0, stream>>>(
        cpart, active, accum, counter, out);
}

// Round 4
// 251.110 us; speedup vs baseline: 2.2126x; 1.1531x over previous
//
#include <hip/hip_runtime.h>
#include <stdint.h>

// ---------------------------------------------------------------------------
// VectorQuantizer: argmin_k ||x_n - c_k||^2 + straight-through out + losses.
//
// Token semantics (R4/R5/R7/R9-verified): candidates by continuous score
// s = ||c||^2 - 2 x.c via fp16 MFMA; exact fp64 re-score; token = lowest
// index within 0.75*ulp_fp32(Dmin) of the minimum.
//
// R11: 122us gemm, latency-bound, ~54MB spill (u1/u2 + hoisted frag cloud).
// R12 FAILED: source-level reg rotation SSA-renamed away.
// R13 FAILED: LDS-staged B at (256,3) -> acc scratch-spill (pipeline regs
//   too fat) + 2.1M bank conflicts ([128][32]hw rows: 8 even-L lanes per
//   quad on one 4-bank group = 8-way).
// R14: u12->LDS + unroll2 + xsq->LDS: memory CLEAN (WRITE 6.8MB, 0 confl,
//   84 VGPR, occ 27%) but 143us -- shallow in-flight lost to R11's deep
//   pipeline. Lesson: depth is the lever; only global_load_lds gives depth
//   at zero VGPR.
// R15: R13 retried with both killers fixed:
//   - B-slice (128x32 f16 = 8KB) dbuf via global_load_lds, XOR slot
//     swizzle slot' = quad ^ ((L>>1)&3) staged through inverse-swizzled
//     GLOBAL addresses (linear LDS dest per DMA semantics). Hand-checked:
//     lanes L=0..7 of a quad cover all 32 banks exactly once.
//   - No persistent fragment state (af transient, u12 in LDS) -> peak
//     ~90 VGPR + 64 acc fits (256,3)'s 170 cap with slack.
//   - One barrier per dc-step = DMA fence; kt-epilogue (~600 VALU)
//     covers next kt's first DMA.
// LDS 50.5KB -> 3 blocks/CU.
// ---------------------------------------------------------------------------

#define N_ROWS 16384
#define DIM    256
#define KCODES 4096
#define NCHUNK 8
#define KC     (KCODES / NCHUNK)   // 512 codes per chunk
#define TM     128                 // rows per block tile
#define TN     128                 // codes per code-tile
#define BK     32                  // K per dc step
#define NKT    (KC / TN)           // 4 code tiles per chunk
#define NDC    (DIM / BK)          // 8 K-steps
#define NSTEP  (NKT * NDC)         // 32 pipeline steps
#define NGRAN  (NCHUNK * 2)        // 16 granules of 256 cols (chunk x chalf)
#define NRB    (N_ROWS / TM)       // 128 row-blocks

typedef float    f32x4 __attribute__((ext_vector_type(4)));
typedef _Float16 f16x8 __attribute__((ext_vector_type(8)));

#define GLOAD_LDS16(g, l) __builtin_amdgcn_global_load_lds(                 \
    (const __attribute__((address_space(1))) void*)(g),                     \
    (__attribute__((address_space(3))) void*)(l), 16, 0, 0)

__device__ __forceinline__ unsigned umin_(unsigned a, unsigned b) { return a < b ? a : b; }
__device__ __forceinline__ unsigned umax_(unsigned a, unsigned b) { return a > b ? a : b; }

// order-preserving float->uint key
__device__ __forceinline__ unsigned fkey(float f) {
    unsigned b = __float_as_uint(f);
    return (b & 0x80000000u) ? ~b : (b | 0x80000000u);
}
__device__ __forceinline__ float fkey_inv(unsigned k) {
    unsigned b = (k & 0x80000000u) ? (k ^ 0x80000000u) : ~k;
    return __uint_as_float(b);
}
__device__ __forceinline__ unsigned short f2h(float f) {
    union { _Float16 h; unsigned short u; } cv;
    cv.h = (_Float16)f;            // v_cvt_f16_f32, RNE
    return cv.u;
}

// sorted top-8 insert by (value, index) lexicographic
__device__ __forceinline__ void ins8(float w, int j, float v[8], int id[8]) {
    if (w < v[7] || (w == v[7] && j < id[7])) {
        v[7] = w; id[7] = j;
#pragma unroll
        for (int k = 7; k > 0; --k) {
            if (v[k] < v[k-1] || (v[k] == v[k-1] && id[k] < id[k-1])) {
                float tv = v[k]; v[k] = v[k-1]; v[k-1] = tv;
                int ti = id[k]; id[k] = id[k-1]; id[k-1] = ti;
            }
        }
    }
}

// ---- prep: fp16 cast + row sumsq (fp64->fp32) + buffer init, fused ----
__global__ __launch_bounds__(256) void vq_prep_kernel(
        const float* __restrict__ x, const float* __restrict__ cb,
        unsigned short* __restrict__ xh, unsigned short* __restrict__ ch,
        float* __restrict__ xsq, float* __restrict__ csq,
        unsigned* __restrict__ active, double* __restrict__ accum,
        unsigned* __restrict__ counter) {
    const int b = blockIdx.x, t = threadIdx.x;
    if (b < KCODES / 256) {
        int i = b * 256 + t;
        active[i] = 0u;
        if (i == 0) { accum[0] = 0.0; accum[1] = 0.0; counter[0] = 0u; }
    }
    const size_t NX = (size_t)N_ROWS * DIM;
    size_t e = (size_t)b * 1024 + (size_t)t * 4;
    const float* src; unsigned short* dst; float* sq; size_t off;
    if (e < NX) { src = x;  dst = xh; sq = xsq; off = e; }
    else        { src = cb; dst = ch; sq = csq; off = e - NX; }
    float4 v = *(const float4*)(src + off);
    ushort4 h;
    h.x = f2h(v.x); h.y = f2h(v.y); h.z = f2h(v.z); h.w = f2h(v.w);
    *(ushort4*)(dst + off) = h;
    double s = (double)v.x * v.x + (double)v.y * v.y
             + (double)v.z * v.z + (double)v.w * v.w;
    for (int o = 32; o; o >>= 1) s += __shfl_down(s, o);
    if ((t & 63) == 0) sq[off >> 8] = (float)s;
}

// ---- MFMA candidate GEMM. grid = (NRB, NCHUNK), 256 thr (4 waves).
// B via swizzled global_load_lds dbuf; A direct from L2; u12 state in LDS.
__global__ __launch_bounds__(256, 3) void vq_gemm_kernel(
        const unsigned short* __restrict__ xh_g, const unsigned short* __restrict__ ch_g,
        const float* __restrict__ xsq, const float* __restrict__ csq,
        unsigned* __restrict__ colmin_part, uint2* __restrict__ top2_out) {
    __shared__ __align__(16) unsigned short b_lds[2][TN][BK];  // 16 KB
    __shared__ float    xsq_l[128];
    __shared__ unsigned colmin_l[KC];
    __shared__ uint2    u12_l[16][256];   // 32 KB: per-thread top-2 state

    const int t = threadIdx.x;
    const int wave = t >> 6, lane = t & 63, quad = lane >> 4, L = lane & 15;
    const int whalf = wave >> 1, chalf = wave & 1;
    const int row0  = blockIdx.x * TM;
    const int code0 = blockIdx.y * KC;

    if (t < 128) xsq_l[t] = xsq[row0 + t];
    colmin_l[t] = 0xFFFFFFFFu; colmin_l[t + 256] = 0xFFFFFFFFu;
#pragma unroll
    for (int i = 0; i < 16; ++i)
        u12_l[i][t] = make_uint2(0xFFFFFFFFu, 0xFFFFFFFFu);

    const unsigned short* abase =
        xh_g + ((size_t)(row0 + whalf * 64 + L) * DIM + quad * 8);

    // Staging (swizzled): LDS 16B-chunk j holds global (row j>>2,
    // slot (j&3)^((j>>3)&3)).  (j>>3) == row>>1 exactly, so stored slot t
    // at row r carries global slot t^((r>>1)&3) -- involution.
    // Linear LDS dest = base + j*16 (DMA writes wave-uniform base+lane*16).
    auto stageB = [&](int buf, int kt_, int dc_) {
        const unsigned short* bsrc =
            ch_g + (size_t)(code0 + kt_ * TN) * DIM + dc_ * BK;
        unsigned short* dst = &b_lds[buf][0][0];
#pragma unroll
        for (int k = 0; k < 2; ++k) {
            const int j = t + k * 256;
            const int r = j >> 2, sg = (j & 3) ^ ((j >> 3) & 3);
            GLOAD_LDS16(bsrc + (size_t)r * DIM + sg * 8, dst + (size_t)j * 8);
        }
    };

    const int bslot = (L >> 1) & 3;     // read-side swizzle term

    // prologue: first B slice in flight before first barrier
    stageB(0, 0, 0);

    for (int kt = 0; kt < NKT; ++kt) {
        const int cb0 = code0 + kt * TN;
        f32x4 acc[4][4];
#pragma unroll
        for (int mt = 0; mt < 4; ++mt)
#pragma unroll
            for (int nt = 0; nt < 4; ++nt) acc[mt][nt] = (f32x4){0.f, 0.f, 0.f, 0.f};

#pragma unroll 1
        for (int dc = 0; dc < NDC; ++dc) {
            const int s = kt * NDC + dc, cur = s & 1;
            __syncthreads();     // vmcnt(0) drain => buf[cur] staged; all
                                 // waves done reading buf[cur^1]
            if (s < NSTEP - 1)
                stageB(cur ^ 1, (s + 1) >> 3, (s + 1) & 7);

            f16x8 af[4], bf[4];
#pragma unroll
            for (int mt = 0; mt < 4; ++mt)
                af[mt] = *(const f16x8*)(abase + (size_t)mt * 16 * DIM + dc * BK);
#pragma unroll
            for (int nt = 0; nt < 4; ++nt)
                bf[nt] = *(const f16x8*)
                    &b_lds[cur][chalf * 64 + nt * 16 + L][(quad ^ bslot) * 8];
#pragma unroll
            for (int mt = 0; mt < 4; ++mt)
#pragma unroll
                for (int nt = 0; nt < 4; ++nt)
                    acc[mt][nt] = __builtin_amdgcn_mfma_f32_16x16x32_f16(
                        af[mt], bf[nt], acc[mt][nt], 0, 0, 0);
        }

        // ---- epilogue: packed-key top-2 upkeep (LDS state) + column-min.
        // Overlaps the already-issued DMA of next kt's first slice.
        float csq4[4]; unsigned colf[4];
        float dmin[4] = {3.4e38f, 3.4e38f, 3.4e38f, 3.4e38f};
#pragma unroll
        for (int nt = 0; nt < 4; ++nt) {
            csq4[nt] = csq[cb0 + chalf * 64 + nt * 16 + L];
            colf[nt] = (unsigned)(kt * 128 + chalf * 64 + nt * 16 + L);
        }
#pragma unroll
        for (int mt = 0; mt < 4; ++mt) {
            const f32x4 xq = *(const f32x4*)&xsq_l[whalf * 64 + mt * 16 + quad * 4];
#pragma unroll
            for (int reg = 0; reg < 4; ++reg) {
                const int i = mt * 4 + reg;
                uint2 e = u12_l[i][t];
#pragma unroll
                for (int nt = 0; nt < 4; ++nt) {
                    float s = fmaf(-2.0f, acc[mt][nt][reg], csq4[nt]);
                    unsigned key = (fkey(s) & 0xFFFFFE00u) | colf[nt];
                    unsigned lo = umin_(e.x, key);
                    e.y = umin_(e.y, umax_(e.x, key));
                    e.x = lo;
                    dmin[nt] = fminf(dmin[nt], xq[reg] + s);
                }
                u12_l[i][t] = e;
            }
        }
#pragma unroll
        for (int nt = 0; nt < 4; ++nt) {
            unsigned dk = fkey(dmin[nt]);
            dk = umin_(dk, (unsigned)__shfl_xor((int)dk, 16));
            dk = umin_(dk, (unsigned)__shfl_xor((int)dk, 32));
            if (quad == 0)
                atomicMin(&colmin_l[kt * TN + chalf * 64 + nt * 16 + L], dk);
        }
    }

    // ---- once per block: butterfly-merge top-2 across the 16 L-lanes ----
    unsigned u1[16], u2[16];
#pragma unroll
    for (int i = 0; i < 16; ++i) {
        uint2 e = u12_l[i][t];
        u1[i] = e.x; u2[i] = e.y;
    }
#pragma unroll
    for (int i = 0; i < 16; ++i) {
#pragma unroll
        for (int st = 1; st < 16; st <<= 1) {
            unsigned w1 = (unsigned)__shfl_xor((int)u1[i], st);
            unsigned w2 = (unsigned)__shfl_xor((int)u2[i], st);
            unsigned a = umin_(u1[i], w1), b = umax_(u1[i], w1);
            u1[i] = a;
            u2[i] = umin_(umin_(u2[i], w2), b);
        }
    }
    if (L == 0) {
        const size_t gbase = (size_t)(blockIdx.y * 2 + chalf) * N_ROWS;
#pragma unroll
        for (int mt = 0; mt < 4; ++mt)
#pragma unroll
            for (int reg = 0; reg < 4; ++reg) {
                const int row = row0 + whalf * 64 + mt * 16 + quad * 4 + reg;
                top2_out[gbase + row] = make_uint2(u1[mt * 4 + reg], u2[mt * 4 + reg]);
            }
    }

    // ---- flush block-local colmin to private slice (plain stores) ----
    __syncthreads();
    unsigned* cp = colmin_part + (size_t)blockIdx.x * KCODES + code0;
    cp[t]       = colmin_l[t];
    cp[t + 256] = colmin_l[t + 256];
}

// ---- refine + gather + MSE, fused. grid = N_ROWS/4, 1 wave per row. ----
// Fast path: candidate gap > 1e-2 => winner certain, no fp64. Slow path:
// all 8 candidates, fully unrolled fp64 re-score, token = lowest index
// within 0.75*ulp_fp32(Dmin). No dynamic indexing (no scratch).
__global__ __launch_bounds__(256) void vq_refine_kernel(
        const float* __restrict__ x, const float* __restrict__ cb,
        const uint2* __restrict__ top2, unsigned* __restrict__ active,
        float* __restrict__ out, double* __restrict__ accum) {
    __shared__ double wsum[4];
    const int wave = threadIdx.x >> 6, lane = threadIdx.x & 63;
    const int row  = blockIdx.x * 4 + wave;

    float v[8]; int id[8];
#pragma unroll
    for (int k = 0; k < 8; ++k) { v[k] = 3.4e38f; id[k] = 0x7FFFFFFF; }
#pragma unroll
    for (int g = 0; g < NGRAN; ++g) {
        uint2 e = top2[(size_t)g * N_ROWS + row];
        const int cbase = (g >> 1) * KC;
        ins8(fkey_inv(e.x & 0xFFFFFE00u), cbase + (int)(e.x & 0x1FFu), v, id);
        ins8(fkey_inv(e.y & 0xFFFFFE00u), cbase + (int)(e.y & 0x1FFu), v, id);
    }

    float4 xv = ((const float4*)(x + (size_t)row * DIM))[lane];
    int tok;
    if (v[1] > v[0] + 1.0e-2f) {
        tok = id[0];
    } else {
        double xs64 = (double)xv.x * xv.x + (double)xv.y * xv.y
                    + (double)xv.z * xv.z + (double)xv.w * xv.w;
        double dd[8], cc2[8];
#pragma unroll
        for (int k = 0; k < 8; ++k) {
            float4 c4 = ((const float4*)(cb + (size_t)id[k] * DIM))[lane];
            dd[k]  = (double)xv.x * c4.x + (double)xv.y * c4.y
                   + (double)xv.z * c4.z + (double)xv.w * c4.w;
            cc2[k] = (double)c4.x * c4.x + (double)c4.y * c4.y
                   + (double)c4.z * c4.z + (double)c4.w * c4.w;
        }
#pragma unroll
        for (int o = 32; o; o >>= 1) {
            xs64 += __shfl_down(xs64, o);
#pragma unroll
            for (int k = 0; k < 8; ++k) {
                dd[k]  += __shfl_down(dd[k], o);
                cc2[k] += __shfl_down(cc2[k], o);
            }
        }
        if (lane == 0) {
            double D[8], Dmin = 1e300;
#pragma unroll
            for (int k = 0; k < 8; ++k) {
                D[k] = xs64 + cc2[k] - 2.0 * dd[k];
                Dmin = fmin(Dmin, D[k]);
            }
            int e2; frexp(Dmin, &e2);
            double U   = ldexp(1.0, e2 - 1 - 23);     // ulp_fp32(Dmin)
            double thr = Dmin + 0.75 * U;
            tok = 0x7FFFFFFF;
#pragma unroll
            for (int k = 0; k < 8; ++k)
                if (D[k] <= thr && id[k] < tok) tok = id[k];
        }
        tok = __shfl(tok, 0);
    }

    if (lane == 0) active[tok] = 1u;
    float4 sel = ((const float4*)(cb + (size_t)tok * DIM))[lane];
    ((float4*)out)[(size_t)row * 64 + lane] = sel;
    float dx = sel.x - xv.x, dy = sel.y - xv.y, dz = sel.z - xv.z, dw = sel.w - xv.w;
    float s = dx * dx + dy * dy + dz * dz + dw * dw;
    for (int o = 32; o; o >>= 1) s += __shfl_down(s, o);
    if (lane == 0) wsum[wave] = (double)s;
    __syncthreads();
    if (threadIdx.x == 0) atomicAdd(accum, wsum[0] + wsum[1] + wsum[2] + wsum[3]);
}

// ---- final: 128-way colmin reduction + entropy + loss. grid = 16 blocks.
// Each block reduces 256 codes over the 128 row-block partials, adds its
// inactive-code entropy partial; the 16th finisher computes the loss.
__global__ __launch_bounds__(256) void vq_final_kernel(
        const unsigned* __restrict__ colmin_part, const unsigned* __restrict__ active,
        double* __restrict__ accum, unsigned* __restrict__ counter,
        float* __restrict__ out) {
    __shared__ double red[256];
    const int t = threadIdx.x;
    const int c = blockIdx.x * 256 + t;
    unsigned m = 0xFFFFFFFFu;
#pragma unroll 8
    for (int rb = 0; rb < NRB; ++rb)
        m = umin_(m, colmin_part[(size_t)rb * KCODES + c]);
    red[t] = (active[c] == 0u) ? (double)fkey_inv(m) : 0.0;
    __syncthreads();
    for (int o = 128; o; o >>= 1) {
        if (t < o) red[t] += red[t + o];
        __syncthreads();
    }
    if (t == 0) {
        atomicAdd(&accum[1], red[0]);
        __threadfence();
        unsigned old = atomicAdd(counter, 1u);
        if (old == 15u) {
            __threadfence();
            double ent = atomicAdd(&accum[1], 0.0);   // atomic read
            double loss = 1.25 * (accum[0] / (double)((size_t)N_ROWS * DIM))
                        + 0.02 * (ent / (double)KCODES);
            out[(size_t)N_ROWS * DIM] = (float)loss;
        }
    }
}

extern "C" void kernel_launch(void* const* d_in, const int* in_sizes, int n_in,
                              void* d_out, int out_size, void* d_ws, size_t ws_size,
                              hipStream_t stream) {
    const float* x  = (const float*)d_in[0];   // [16384, 256]
    const float* cb = (const float*)d_in[1];   // [4096, 256]
    float* out = (float*)d_out;                // [16384*256] ++ [1] loss

    char* ws = (char*)d_ws;
    float*    xsq     = (float*)(ws + 0);                      // 64 KB
    float*    csq     = (float*)(ws + 65536);                  // 16 KB
    unsigned* active  = (unsigned*)(ws + 81920);               // 16 KB
    double*   accum   = (double*)(ws + 98304);                 // 256 B (mse, entropy)
    unsigned* counter = (unsigned*)(ws + 98560);               // 64 B
    uint2*    top2    = (uint2*)(ws + 131072);                 // 2 MB (16 granules)
    unsigned* cpart   = (unsigned*)(ws + 2228224);             // 2 MB (128 x 4096)
    unsigned short* xh_g = (unsigned short*)(ws + 4325376);    // 8 MB
    unsigned short* ch_g = (unsigned short*)(ws + 12713984);   // 2 MB (~14.2 MB)

    vq_prep_kernel<<<((N_ROWS + KCODES) * DIM) / 1024, 256, 0, stream>>>(
        x, cb, xh_g, ch_g, xsq, csq, active, accum, counter);
    vq_gemm_kernel<<<dim3(NRB, NCHUNK), 256, 0, stream>>>(
        xh_g, ch_g, xsq, csq, cpart, top2);
    vq_refine_kernel<<<N_ROWS / 4, 256, 0, stream>>>(
        x, cb, top2, active, out, accum);
    vq_final_kernel<<<KCODES / 256, 256, 0, stream>>>(
        cpart, active, accum, counter, out);
}

// Round 5
// 223.536 us; speedup vs baseline: 2.4855x; 1.1234x over previous
//
#include <hip/hip_runtime.h>
#include <stdint.h>

// ---------------------------------------------------------------------------
// VectorQuantizer: argmin_k ||x_n - c_k||^2 + straight-through out + losses.
//
// Token semantics (R4/R5/R7/R9-verified): candidates by continuous score
// s = ||c||^2 - 2 x.c via fp16 MFMA; exact fp64 re-score; token = lowest
// index within 0.75*ulp_fp32(Dmin) of the minimum.
//
// R11: 122us gemm, latency-bound, ~54MB spill. R12 FAILED (SSA rename).
// R13 FAILED (acc spill at (256,3) + 2.1M bank conflicts).
// R14: u12->LDS, clean but shallow (143us).
// R15: swizzled global_load_lds dbuf B + u12/xsq in LDS: gemm 103us,
//   WRITE 4MB (zero spill), 0 conflicts, VGPR 68. Remaining critical path:
//   4 A-fragment global loads (~200-400cy L2) inside every dc-step, re-read
//   every kt (4x).
// R16: A panel persistent in registers. Wave's 32 A-fragments (128 VGPR)
//   loaded once in prologue; steady-state step = barrier -> stageB DMA
//   (0 VGPR) -> 4x ds_read_b128 -> 16 independent MFMAs (~200cy path).
//   Budget 128(A)+64(acc)+~30 = ~222 < 256 cap at (256,2). dc loop fully
//   unrolled so all afr[][] indices and buf parity (cur=dc&1) are
//   compile-time (no scratch, rule: static indexing only).
// ---------------------------------------------------------------------------

#define N_ROWS 16384
#define DIM    256
#define KCODES 4096
#define NCHUNK 8
#define KC     (KCODES / NCHUNK)   // 512 codes per chunk
#define TM     128                 // rows per block tile
#define TN     128                 // codes per code-tile
#define BK     32                  // K per dc step
#define NKT    (KC / TN)           // 4 code tiles per chunk
#define NDC    (DIM / BK)          // 8 K-steps
#define NSTEP  (NKT * NDC)         // 32 pipeline steps
#define NGRAN  (NCHUNK * 2)        // 16 granules of 256 cols (chunk x chalf)
#define NRB    (N_ROWS / TM)       // 128 row-blocks

typedef float    f32x4 __attribute__((ext_vector_type(4)));
typedef _Float16 f16x8 __attribute__((ext_vector_type(8)));

#define GLOAD_LDS16(g, l) __builtin_amdgcn_global_load_lds(                 \
    (const __attribute__((address_space(1))) void*)(g),                     \
    (__attribute__((address_space(3))) void*)(l), 16, 0, 0)

__device__ __forceinline__ unsigned umin_(unsigned a, unsigned b) { return a < b ? a : b; }
__device__ __forceinline__ unsigned umax_(unsigned a, unsigned b) { return a > b ? a : b; }

// order-preserving float->uint key
__device__ __forceinline__ unsigned fkey(float f) {
    unsigned b = __float_as_uint(f);
    return (b & 0x80000000u) ? ~b : (b | 0x80000000u);
}
__device__ __forceinline__ float fkey_inv(unsigned k) {
    unsigned b = (k & 0x80000000u) ? (k ^ 0x80000000u) : ~k;
    return __uint_as_float(b);
}
__device__ __forceinline__ unsigned short f2h(float f) {
    union { _Float16 h; unsigned short u; } cv;
    cv.h = (_Float16)f;            // v_cvt_f16_f32, RNE
    return cv.u;
}

// sorted top-8 insert by (value, index) lexicographic
__device__ __forceinline__ void ins8(float w, int j, float v[8], int id[8]) {
    if (w < v[7] || (w == v[7] && j < id[7])) {
        v[7] = w; id[7] = j;
#pragma unroll
        for (int k = 7; k > 0; --k) {
            if (v[k] < v[k-1] || (v[k] == v[k-1] && id[k] < id[k-1])) {
                float tv = v[k]; v[k] = v[k-1]; v[k-1] = tv;
                int ti = id[k]; id[k] = id[k-1]; id[k-1] = ti;
            }
        }
    }
}

// ---- prep: fp16 cast + row sumsq (fp64->fp32) + buffer init, fused ----
__global__ __launch_bounds__(256) void vq_prep_kernel(
        const float* __restrict__ x, const float* __restrict__ cb,
        unsigned short* __restrict__ xh, unsigned short* __restrict__ ch,
        float* __restrict__ xsq, float* __restrict__ csq,
        unsigned* __restrict__ active, double* __restrict__ accum,
        unsigned* __restrict__ counter) {
    const int b = blockIdx.x, t = threadIdx.x;
    if (b < KCODES / 256) {
        int i = b * 256 + t;
        active[i] = 0u;
        if (i == 0) { accum[0] = 0.0; accum[1] = 0.0; counter[0] = 0u; }
    }
    const size_t NX = (size_t)N_ROWS * DIM;
    size_t e = (size_t)b * 1024 + (size_t)t * 4;
    const float* src; unsigned short* dst; float* sq; size_t off;
    if (e < NX) { src = x;  dst = xh; sq = xsq; off = e; }
    else        { src = cb; dst = ch; sq = csq; off = e - NX; }
    float4 v = *(const float4*)(src + off);
    ushort4 h;
    h.x = f2h(v.x); h.y = f2h(v.y); h.z = f2h(v.z); h.w = f2h(v.w);
    *(ushort4*)(dst + off) = h;
    double s = (double)v.x * v.x + (double)v.y * v.y
             + (double)v.z * v.z + (double)v.w * v.w;
    for (int o = 32; o; o >>= 1) s += __shfl_down(s, o);
    if ((t & 63) == 0) sq[off >> 8] = (float)s;
}

// ---- MFMA candidate GEMM. grid = (NRB, NCHUNK), 256 thr (4 waves).
// A panel persistent in regs; B via swizzled global_load_lds dbuf.
__global__ __launch_bounds__(256, 2) void vq_gemm_kernel(
        const unsigned short* __restrict__ xh_g, const unsigned short* __restrict__ ch_g,
        const float* __restrict__ xsq, const float* __restrict__ csq,
        unsigned* __restrict__ colmin_part, uint2* __restrict__ top2_out) {
    __shared__ __align__(16) unsigned short b_lds[2][TN][BK];  // 16 KB
    __shared__ float    xsq_l[128];
    __shared__ unsigned colmin_l[KC];
    __shared__ uint2    u12_l[16][256];   // 32 KB: per-thread top-2 state

    const int t = threadIdx.x;
    const int wave = t >> 6, lane = t & 63, quad = lane >> 4, L = lane & 15;
    const int whalf = wave >> 1, chalf = wave & 1;
    const int row0  = blockIdx.x * TM;
    const int code0 = blockIdx.y * KC;

    if (t < 128) xsq_l[t] = xsq[row0 + t];
    colmin_l[t] = 0xFFFFFFFFu; colmin_l[t + 256] = 0xFFFFFFFFu;
#pragma unroll
    for (int i = 0; i < 16; ++i)
        u12_l[i][t] = make_uint2(0xFFFFFFFFu, 0xFFFFFFFFu);

    const unsigned short* abase =
        xh_g + ((size_t)(row0 + whalf * 64 + L) * DIM + quad * 8);

    // Staging (swizzled): LDS 16B-chunk j holds global (row j>>2,
    // slot (j&3)^((j>>3)&3)) -- slot t at row r carries global slot
    // t^((r>>1)&3), an involution. Linear LDS dest per DMA semantics.
    auto stageB = [&](int buf, int kt_, int dc_) {
        const unsigned short* bsrc =
            ch_g + (size_t)(code0 + kt_ * TN) * DIM + dc_ * BK;
        unsigned short* dst = &b_lds[buf][0][0];
#pragma unroll
        for (int k = 0; k < 2; ++k) {
            const int j = t + k * 256;
            const int r = j >> 2, sg = (j & 3) ^ ((j >> 3) & 3);
            GLOAD_LDS16(bsrc + (size_t)r * DIM + sg * 8, dst + (size_t)j * 8);
        }
    };

    const int bslot = (L >> 1) & 3;     // read-side swizzle term

    // prologue: first B slice in flight; A panel -> 32 persistent VGPR frags
    stageB(0, 0, 0);
    f16x8 afr[NDC][4];                  // 128 VGPRs, compile-time indexed
#pragma unroll
    for (int dc = 0; dc < NDC; ++dc)
#pragma unroll
        for (int mt = 0; mt < 4; ++mt)
            afr[dc][mt] = *(const f16x8*)(abase + (size_t)mt * 16 * DIM + dc * BK);

    for (int kt = 0; kt < NKT; ++kt) {
        const int cb0 = code0 + kt * TN;
        f32x4 acc[4][4];
#pragma unroll
        for (int mt = 0; mt < 4; ++mt)
#pragma unroll
            for (int nt = 0; nt < 4; ++nt) acc[mt][nt] = (f32x4){0.f, 0.f, 0.f, 0.f};

#pragma unroll
        for (int dc = 0; dc < NDC; ++dc) {
            const int cur = dc & 1;     // compile-time buffer parity
            __syncthreads();     // vmcnt(0) drain => buf[cur] staged; all
                                 // waves done reading buf[cur^1]
            if (!(kt == NKT - 1 && dc == NDC - 1))
                stageB(cur ^ 1, kt + (dc == NDC - 1), (dc + 1) & 7);

            f16x8 bf[4];
#pragma unroll
            for (int nt = 0; nt < 4; ++nt)
                bf[nt] = *(const f16x8*)
                    &b_lds[cur][chalf * 64 + nt * 16 + L][(quad ^ bslot) * 8];
#pragma unroll
            for (int mt = 0; mt < 4; ++mt)
#pragma unroll
                for (int nt = 0; nt < 4; ++nt)
                    acc[mt][nt] = __builtin_amdgcn_mfma_f32_16x16x32_f16(
                        afr[dc][mt], bf[nt], acc[mt][nt], 0, 0, 0);
        }

        // ---- epilogue: packed-key top-2 upkeep (LDS state) + column-min.
        // Overlaps the already-issued DMA of next kt's first slice.
        float csq4[4]; unsigned colf[4];
        float dmin[4] = {3.4e38f, 3.4e38f, 3.4e38f, 3.4e38f};
#pragma unroll
        for (int nt = 0; nt < 4; ++nt) {
            csq4[nt] = csq[cb0 + chalf * 64 + nt * 16 + L];
            colf[nt] = (unsigned)(kt * 128 + chalf * 64 + nt * 16 + L);
        }
#pragma unroll
        for (int mt = 0; mt < 4; ++mt) {
            const f32x4 xq = *(const f32x4*)&xsq_l[whalf * 64 + mt * 16 + quad * 4];
#pragma unroll
            for (int reg = 0; reg < 4; ++reg) {
                const int i = mt * 4 + reg;
                uint2 e = u12_l[i][t];
#pragma unroll
                for (int nt = 0; nt < 4; ++nt) {
                    float s = fmaf(-2.0f, acc[mt][nt][reg], csq4[nt]);
                    unsigned key = (fkey(s) & 0xFFFFFE00u) | colf[nt];
                    unsigned lo = umin_(e.x, key);
                    e.y = umin_(e.y, umax_(e.x, key));
                    e.x = lo;
                    dmin[nt] = fminf(dmin[nt], xq[reg] + s);
                }
                u12_l[i][t] = e;
            }
        }
#pragma unroll
        for (int nt = 0; nt < 4; ++nt) {
            unsigned dk = fkey(dmin[nt]);
            dk = umin_(dk, (unsigned)__shfl_xor((int)dk, 16));
            dk = umin_(dk, (unsigned)__shfl_xor((int)dk, 32));
            if (quad == 0)
                atomicMin(&colmin_l[kt * TN + chalf * 64 + nt * 16 + L], dk);
        }
    }

    // ---- once per block: butterfly-merge top-2 across the 16 L-lanes ----
    unsigned u1[16], u2[16];
#pragma unroll
    for (int i = 0; i < 16; ++i) {
        uint2 e = u12_l[i][t];
        u1[i] = e.x; u2[i] = e.y;
    }
#pragma unroll
    for (int i = 0; i < 16; ++i) {
#pragma unroll
        for (int st = 1; st < 16; st <<= 1) {
            unsigned w1 = (unsigned)__shfl_xor((int)u1[i], st);
            unsigned w2 = (unsigned)__shfl_xor((int)u2[i], st);
            unsigned a = umin_(u1[i], w1), b = umax_(u1[i], w1);
            u1[i] = a;
            u2[i] = umin_(umin_(u2[i], w2), b);
        }
    }
    if (L == 0) {
        const size_t gbase = (size_t)(blockIdx.y * 2 + chalf) * N_ROWS;
#pragma unroll
        for (int mt = 0; mt < 4; ++mt)
#pragma unroll
            for (int reg = 0; reg < 4; ++reg) {
                const int row = row0 + whalf * 64 + mt * 16 + quad * 4 + reg;
                top2_out[gbase + row] = make_uint2(u1[mt * 4 + reg], u2[mt * 4 + reg]);
            }
    }

    // ---- flush block-local colmin to private slice (plain stores) ----
    __syncthreads();
    unsigned* cp = colmin_part + (size_t)blockIdx.x * KCODES + code0;
    cp[t]       = colmin_l[t];
    cp[t + 256] = colmin_l[t + 256];
}

// ---- refine + gather + MSE, fused. grid = N_ROWS/4, 1 wave per row. ----
// Fast path: candidate gap > 1e-2 => winner certain, no fp64. Slow path:
// all 8 candidates, fully unrolled fp64 re-score, token = lowest index
// within 0.75*ulp_fp32(Dmin). No dynamic indexing (no scratch).
__global__ __launch_bounds__(256) void vq_refine_kernel(
        const float* __restrict__ x, const float* __restrict__ cb,
        const uint2* __restrict__ top2, unsigned* __restrict__ active,
        float* __restrict__ out, double* __restrict__ accum) {
    __shared__ double wsum[4];
    const int wave = threadIdx.x >> 6, lane = threadIdx.x & 63;
    const int row  = blockIdx.x * 4 + wave;

    float v[8]; int id[8];
#pragma unroll
    for (int k = 0; k < 8; ++k) { v[k] = 3.4e38f; id[k] = 0x7FFFFFFF; }
#pragma unroll
    for (int g = 0; g < NGRAN; ++g) {
        uint2 e = top2[(size_t)g * N_ROWS + row];
        const int cbase = (g >> 1) * KC;
        ins8(fkey_inv(e.x & 0xFFFFFE00u), cbase + (int)(e.x & 0x1FFu), v, id);
        ins8(fkey_inv(e.y & 0xFFFFFE00u), cbase + (int)(e.y & 0x1FFu), v, id);
    }

    float4 xv = ((const float4*)(x + (size_t)row * DIM))[lane];
    int tok;
    if (v[1] > v[0] + 1.0e-2f) {
        tok = id[0];
    } else {
        double xs64 = (double)xv.x * xv.x + (double)xv.y * xv.y
                    + (double)xv.z * xv.z + (double)xv.w * xv.w;
        double dd[8], cc2[8];
#pragma unroll
        for (int k = 0; k < 8; ++k) {
            float4 c4 = ((const float4*)(cb + (size_t)id[k] * DIM))[lane];
            dd[k]  = (double)xv.x * c4.x + (double)xv.y * c4.y
                   + (double)xv.z * c4.z + (double)xv.w * c4.w;
            cc2[k] = (double)c4.x * c4.x + (double)c4.y * c4.y
                   + (double)c4.z * c4.z + (double)c4.w * c4.w;
        }
#pragma unroll
        for (int o = 32; o; o >>= 1) {
            xs64 += __shfl_down(xs64, o);
#pragma unroll
            for (int k = 0; k < 8; ++k) {
                dd[k]  += __shfl_down(dd[k], o);
                cc2[k] += __shfl_down(cc2[k], o);
            }
        }
        if (lane == 0) {
            double D[8], Dmin = 1e300;
#pragma unroll
            for (int k = 0; k < 8; ++k) {
                D[k] = xs64 + cc2[k] - 2.0 * dd[k];
                Dmin = fmin(Dmin, D[k]);
            }
            int e2; frexp(Dmin, &e2);
            double U   = ldexp(1.0, e2 - 1 - 23);     // ulp_fp32(Dmin)
            double thr = Dmin + 0.75 * U;
            tok = 0x7FFFFFFF;
#pragma unroll
            for (int k = 0; k < 8; ++k)
                if (D[k] <= thr && id[k] < tok) tok = id[k];
        }
        tok = __shfl(tok, 0);
    }

    if (lane == 0) active[tok] = 1u;
    float4 sel = ((const float4*)(cb + (size_t)tok * DIM))[lane];
    ((float4*)out)[(size_t)row * 64 + lane] = sel;
    float dx = sel.x - xv.x, dy = sel.y - xv.y, dz = sel.z - xv.z, dw = sel.w - xv.w;
    float s = dx * dx + dy * dy + dz * dz + dw * dw;
    for (int o = 32; o; o >>= 1) s += __shfl_down(s, o);
    if (lane == 0) wsum[wave] = (double)s;
    __syncthreads();
    if (threadIdx.x == 0) atomicAdd(accum, wsum[0] + wsum[1] + wsum[2] + wsum[3]);
}

// ---- final: 128-way colmin reduction + entropy + loss. grid = 16 blocks.
// Each block reduces 256 codes over the 128 row-block partials, adds its
// inactive-code entropy partial; the 16th finisher computes the loss.
__global__ __launch_bounds__(256) void vq_final_kernel(
        const unsigned* __restrict__ colmin_part, const unsigned* __restrict__ active,
        double* __restrict__ accum, unsigned* __restrict__ counter,
        float* __restrict__ out) {
    __shared__ double red[256];
    const int t = threadIdx.x;
    const int c = blockIdx.x * 256 + t;
    unsigned m = 0xFFFFFFFFu;
#pragma unroll 8
    for (int rb = 0; rb < NRB; ++rb)
        m = umin_(m, colmin_part[(size_t)rb * KCODES + c]);
    red[t] = (active[c] == 0u) ? (double)fkey_inv(m) : 0.0;
    __syncthreads();
    for (int o = 128; o; o >>= 1) {
        if (t < o) red[t] += red[t + o];
        __syncthreads();
    }
    if (t == 0) {
        atomicAdd(&accum[1], red[0]);
        __threadfence();
        unsigned old = atomicAdd(counter, 1u);
        if (old == 15u) {
            __threadfence();
            double ent = atomicAdd(&accum[1], 0.0);   // atomic read
            double loss = 1.25 * (accum[0] / (double)((size_t)N_ROWS * DIM))
                        + 0.02 * (ent / (double)KCODES);
            out[(size_t)N_ROWS * DIM] = (float)loss;
        }
    }
}

extern "C" void kernel_launch(void* const* d_in, const int* in_sizes, int n_in,
                              void* d_out, int out_size, void* d_ws, size_t ws_size,
                              hipStream_t stream) {
    const float* x  = (const float*)d_in[0];   // [16384, 256]
    const float* cb = (const float*)d_in[1];   // [4096, 256]
    float* out = (float*)d_out;                // [16384*256] ++ [1] loss

    char* ws = (char*)d_ws;
    float*    xsq     = (float*)(ws + 0);                      // 64 KB
    float*    csq     = (float*)(ws + 65536);                  // 16 KB
    unsigned* active  = (unsigned*)(ws + 81920);               // 16 KB
    double*   accum   = (double*)(ws + 98304);                 // 256 B (mse, entropy)
    unsigned* counter = (unsigned*)(ws + 98560);               // 64 B
    uint2*    top2    = (uint2*)(ws + 131072);                 // 2 MB (16 granules)
    unsigned* cpart   = (unsigned*)(ws + 2228224);             // 2 MB (128 x 4096)
    unsigned short* xh_g = (unsigned short*)(ws + 4325376);    // 8 MB
    unsigned short* ch_g = (unsigned short*)(ws + 12713984);   // 2 MB (~14.2 MB)

    vq_prep_kernel<<<((N_ROWS + KCODES) * DIM) / 1024, 256, 0, stream>>>(
        x, cb, xh_g, ch_g, xsq, csq, active, accum, counter);
    vq_gemm_kernel<<<dim3(NRB, NCHUNK), 256, 0, stream>>>(
        xh_g, ch_g, xsq, csq, cpart, top2);
    vq_refine_kernel<<<N_ROWS / 4, 256, 0, stream>>>(
        x, cb, top2, active, out, accum);
    vq_final_kernel<<<KCODES / 256, 256, 0, stream>>>(
        cpart, active, accum, counter, out);
}

// Round 6
// 203.023 us; speedup vs baseline: 2.7367x; 1.1010x over previous
//
#include <hip/hip_runtime.h>
#include <stdint.h>

// ---------------------------------------------------------------------------
// VectorQuantizer: argmin_k ||x_n - c_k||^2 + straight-through out + losses.
//
// Token semantics (R4/R5/R7/R9-verified): candidates by continuous score
// s = ||c||^2 - 2 x.c via fp16 MFMA; exact fp64 re-score; token = lowest
// index within 0.75*ulp_fp32(Dmin) of the minimum.
//
// R11: 122us gemm, latency-bound, ~54MB spill. R12 FAILED (SSA rename).
// R13 FAILED (acc spill + bank conflicts). R14: u12->LDS, shallow (143us).
// R15: swizzled global_load_lds dbuf B: gemm 103us, zero spill/conflicts.
// R16: A panel persistent in 128 VGPRs: gemm <80us, total 223us.
// R17: refine was the new #1 (80us, VALU 57%, HBM 6%): 32 serial ins8
//   (~300-op dependent chain, redundant on all 64 lanes). Replaced with
//   lane-parallel selection: candidate l -> lane l as u64 key
//   (score32|id32) == same (v,id) lexicographic order; (min1,min2) via one
//   6-step butterfly (fast path); rare slow path recovers the IDENTICAL
//   top-8 set by 8x extract-min, then unchanged fp64 re-score. Tokens
//   bit-identical to R16.
// ---------------------------------------------------------------------------

#define N_ROWS 16384
#define DIM    256
#define KCODES 4096
#define NCHUNK 8
#define KC     (KCODES / NCHUNK)   // 512 codes per chunk
#define TM     128                 // rows per block tile
#define TN     128                 // codes per code-tile
#define BK     32                  // K per dc step
#define NKT    (KC / TN)           // 4 code tiles per chunk
#define NDC    (DIM / BK)          // 8 K-steps
#define NSTEP  (NKT * NDC)         // 32 pipeline steps
#define NGRAN  (NCHUNK * 2)        // 16 granules of 256 cols (chunk x chalf)
#define NRB    (N_ROWS / TM)       // 128 row-blocks

typedef float    f32x4 __attribute__((ext_vector_type(4)));
typedef _Float16 f16x8 __attribute__((ext_vector_type(8)));

#define GLOAD_LDS16(g, l) __builtin_amdgcn_global_load_lds(                 \
    (const __attribute__((address_space(1))) void*)(g),                     \
    (__attribute__((address_space(3))) void*)(l), 16, 0, 0)

__device__ __forceinline__ unsigned umin_(unsigned a, unsigned b) { return a < b ? a : b; }
__device__ __forceinline__ unsigned umax_(unsigned a, unsigned b) { return a > b ? a : b; }
__device__ __forceinline__ unsigned long long umin64_(unsigned long long a,
                                                      unsigned long long b) {
    return a < b ? a : b;
}
__device__ __forceinline__ unsigned long long umax64_(unsigned long long a,
                                                      unsigned long long b) {
    return a > b ? a : b;
}

// order-preserving float->uint key
__device__ __forceinline__ unsigned fkey(float f) {
    unsigned b = __float_as_uint(f);
    return (b & 0x80000000u) ? ~b : (b | 0x80000000u);
}
__device__ __forceinline__ float fkey_inv(unsigned k) {
    unsigned b = (k & 0x80000000u) ? (k ^ 0x80000000u) : ~k;
    return __uint_as_float(b);
}
__device__ __forceinline__ unsigned short f2h(float f) {
    union { _Float16 h; unsigned short u; } cv;
    cv.h = (_Float16)f;            // v_cvt_f16_f32, RNE
    return cv.u;
}

// ---- prep: fp16 cast + row sumsq (fp64->fp32) + buffer init, fused ----
__global__ __launch_bounds__(256) void vq_prep_kernel(
        const float* __restrict__ x, const float* __restrict__ cb,
        unsigned short* __restrict__ xh, unsigned short* __restrict__ ch,
        float* __restrict__ xsq, float* __restrict__ csq,
        unsigned* __restrict__ active, double* __restrict__ accum,
        unsigned* __restrict__ counter) {
    const int b = blockIdx.x, t = threadIdx.x;
    if (b < KCODES / 256) {
        int i = b * 256 + t;
        active[i] = 0u;
        if (i == 0) { accum[0] = 0.0; accum[1] = 0.0; counter[0] = 0u; }
    }
    const size_t NX = (size_t)N_ROWS * DIM;
    size_t e = (size_t)b * 1024 + (size_t)t * 4;
    const float* src; unsigned short* dst; float* sq; size_t off;
    if (e < NX) { src = x;  dst = xh; sq = xsq; off = e; }
    else        { src = cb; dst = ch; sq = csq; off = e - NX; }
    float4 v = *(const float4*)(src + off);
    ushort4 h;
    h.x = f2h(v.x); h.y = f2h(v.y); h.z = f2h(v.z); h.w = f2h(v.w);
    *(ushort4*)(dst + off) = h;
    double s = (double)v.x * v.x + (double)v.y * v.y
             + (double)v.z * v.z + (double)v.w * v.w;
    for (int o = 32; o; o >>= 1) s += __shfl_down(s, o);
    if ((t & 63) == 0) sq[off >> 8] = (float)s;
}

// ---- MFMA candidate GEMM. grid = (NRB, NCHUNK), 256 thr (4 waves).
// A panel persistent in regs; B via swizzled global_load_lds dbuf.
__global__ __launch_bounds__(256, 2) void vq_gemm_kernel(
        const unsigned short* __restrict__ xh_g, const unsigned short* __restrict__ ch_g,
        const float* __restrict__ xsq, const float* __restrict__ csq,
        unsigned* __restrict__ colmin_part, uint2* __restrict__ top2_out) {
    __shared__ __align__(16) unsigned short b_lds[2][TN][BK];  // 16 KB
    __shared__ float    xsq_l[128];
    __shared__ unsigned colmin_l[KC];
    __shared__ uint2    u12_l[16][256];   // 32 KB: per-thread top-2 state

    const int t = threadIdx.x;
    const int wave = t >> 6, lane = t & 63, quad = lane >> 4, L = lane & 15;
    const int whalf = wave >> 1, chalf = wave & 1;
    const int row0  = blockIdx.x * TM;
    const int code0 = blockIdx.y * KC;

    if (t < 128) xsq_l[t] = xsq[row0 + t];
    colmin_l[t] = 0xFFFFFFFFu; colmin_l[t + 256] = 0xFFFFFFFFu;
#pragma unroll
    for (int i = 0; i < 16; ++i)
        u12_l[i][t] = make_uint2(0xFFFFFFFFu, 0xFFFFFFFFu);

    const unsigned short* abase =
        xh_g + ((size_t)(row0 + whalf * 64 + L) * DIM + quad * 8);

    // Staging (swizzled): LDS 16B-chunk j holds global (row j>>2,
    // slot (j&3)^((j>>3)&3)) -- slot t at row r carries global slot
    // t^((r>>1)&3), an involution. Linear LDS dest per DMA semantics.
    auto stageB = [&](int buf, int kt_, int dc_) {
        const unsigned short* bsrc =
            ch_g + (size_t)(code0 + kt_ * TN) * DIM + dc_ * BK;
        unsigned short* dst = &b_lds[buf][0][0];
#pragma unroll
        for (int k = 0; k < 2; ++k) {
            const int j = t + k * 256;
            const int r = j >> 2, sg = (j & 3) ^ ((j >> 3) & 3);
            GLOAD_LDS16(bsrc + (size_t)r * DIM + sg * 8, dst + (size_t)j * 8);
        }
    };

    const int bslot = (L >> 1) & 3;     // read-side swizzle term

    // prologue: first B slice in flight; A panel -> 32 persistent VGPR frags
    stageB(0, 0, 0);
    f16x8 afr[NDC][4];                  // 128 VGPRs, compile-time indexed
#pragma unroll
    for (int dc = 0; dc < NDC; ++dc)
#pragma unroll
        for (int mt = 0; mt < 4; ++mt)
            afr[dc][mt] = *(const f16x8*)(abase + (size_t)mt * 16 * DIM + dc * BK);

    for (int kt = 0; kt < NKT; ++kt) {
        const int cb0 = code0 + kt * TN;
        f32x4 acc[4][4];
#pragma unroll
        for (int mt = 0; mt < 4; ++mt)
#pragma unroll
            for (int nt = 0; nt < 4; ++nt) acc[mt][nt] = (f32x4){0.f, 0.f, 0.f, 0.f};

#pragma unroll
        for (int dc = 0; dc < NDC; ++dc) {
            const int cur = dc & 1;     // compile-time buffer parity
            __syncthreads();     // vmcnt(0) drain => buf[cur] staged; all
                                 // waves done reading buf[cur^1]
            if (!(kt == NKT - 1 && dc == NDC - 1))
                stageB(cur ^ 1, kt + (dc == NDC - 1), (dc + 1) & 7);

            f16x8 bf[4];
#pragma unroll
            for (int nt = 0; nt < 4; ++nt)
                bf[nt] = *(const f16x8*)
                    &b_lds[cur][chalf * 64 + nt * 16 + L][(quad ^ bslot) * 8];
#pragma unroll
            for (int mt = 0; mt < 4; ++mt)
#pragma unroll
                for (int nt = 0; nt < 4; ++nt)
                    acc[mt][nt] = __builtin_amdgcn_mfma_f32_16x16x32_f16(
                        afr[dc][mt], bf[nt], acc[mt][nt], 0, 0, 0);
        }

        // ---- epilogue: packed-key top-2 upkeep (LDS state) + column-min.
        // Overlaps the already-issued DMA of next kt's first slice.
        float csq4[4]; unsigned colf[4];
        float dmin[4] = {3.4e38f, 3.4e38f, 3.4e38f, 3.4e38f};
#pragma unroll
        for (int nt = 0; nt < 4; ++nt) {
            csq4[nt] = csq[cb0 + chalf * 64 + nt * 16 + L];
            colf[nt] = (unsigned)(kt * 128 + chalf * 64 + nt * 16 + L);
        }
#pragma unroll
        for (int mt = 0; mt < 4; ++mt) {
            const f32x4 xq = *(const f32x4*)&xsq_l[whalf * 64 + mt * 16 + quad * 4];
#pragma unroll
            for (int reg = 0; reg < 4; ++reg) {
                const int i = mt * 4 + reg;
                uint2 e = u12_l[i][t];
#pragma unroll
                for (int nt = 0; nt < 4; ++nt) {
                    float s = fmaf(-2.0f, acc[mt][nt][reg], csq4[nt]);
                    unsigned key = (fkey(s) & 0xFFFFFE00u) | colf[nt];
                    unsigned lo = umin_(e.x, key);
                    e.y = umin_(e.y, umax_(e.x, key));
                    e.x = lo;
                    dmin[nt] = fminf(dmin[nt], xq[reg] + s);
                }
                u12_l[i][t] = e;
            }
        }
#pragma unroll
        for (int nt = 0; nt < 4; ++nt) {
            unsigned dk = fkey(dmin[nt]);
            dk = umin_(dk, (unsigned)__shfl_xor((int)dk, 16));
            dk = umin_(dk, (unsigned)__shfl_xor((int)dk, 32));
            if (quad == 0)
                atomicMin(&colmin_l[kt * TN + chalf * 64 + nt * 16 + L], dk);
        }
    }

    // ---- once per block: butterfly-merge top-2 across the 16 L-lanes ----
    unsigned u1[16], u2[16];
#pragma unroll
    for (int i = 0; i < 16; ++i) {
        uint2 e = u12_l[i][t];
        u1[i] = e.x; u2[i] = e.y;
    }
#pragma unroll
    for (int i = 0; i < 16; ++i) {
#pragma unroll
        for (int st = 1; st < 16; st <<= 1) {
            unsigned w1 = (unsigned)__shfl_xor((int)u1[i], st);
            unsigned w2 = (unsigned)__shfl_xor((int)u2[i], st);
            unsigned a = umin_(u1[i], w1), b = umax_(u1[i], w1);
            u1[i] = a;
            u2[i] = umin_(umin_(u2[i], w2), b);
        }
    }
    if (L == 0) {
        const size_t gbase = (size_t)(blockIdx.y * 2 + chalf) * N_ROWS;
#pragma unroll
        for (int mt = 0; mt < 4; ++mt)
#pragma unroll
            for (int reg = 0; reg < 4; ++reg) {
                const int row = row0 + whalf * 64 + mt * 16 + quad * 4 + reg;
                top2_out[gbase + row] = make_uint2(u1[mt * 4 + reg], u2[mt * 4 + reg]);
            }
    }

    // ---- flush block-local colmin to private slice (plain stores) ----
    __syncthreads();
    unsigned* cp = colmin_part + (size_t)blockIdx.x * KCODES + code0;
    cp[t]       = colmin_l[t];
    cp[t + 256] = colmin_l[t + 256];
}

// ---- refine + gather + MSE, fused. grid = N_ROWS/4, 1 wave per row. ----
// R17: lane-parallel candidate selection. Lane l<32 owns candidate
// (granule l>>1, slot l&1) as u64 key (score32|id32) -- same ordering as
// the old (v,id) lexicographic ins8. Fast path: (min1,min2) butterfly.
// Slow path (rare): 8x extract-min recovers the identical top-8 set, then
// unchanged cooperative fp64 re-score + 0.75*ulp_fp32 tie rule.
__global__ __launch_bounds__(256) void vq_refine_kernel(
        const float* __restrict__ x, const float* __restrict__ cb,
        const uint2* __restrict__ top2, unsigned* __restrict__ active,
        float* __restrict__ out, double* __restrict__ accum) {
    __shared__ double wsum[4];
    const int wave = threadIdx.x >> 6, lane = threadIdx.x & 63;
    const int row  = blockIdx.x * 4 + wave;

    // lane-owned candidate -> packed u64 (quantized-score | id)
    const int g = (lane >> 1) & 15;
    uint2 e = top2[(size_t)g * N_ROWS + row];
    unsigned key = (lane & 1) ? e.y : e.x;
    unsigned idc = (unsigned)((g >> 1) * KC) + (key & 0x1FFu);
    unsigned long long pk =
        ((unsigned long long)(key & 0xFFFFFE00u) << 32) | idc;
    if (lane >= 32) pk = ~0ull;

    // butterfly (min1, min2) across 64 lanes -- wave-uniform result
    unsigned long long m1 = pk, m2 = ~0ull;
#pragma unroll
    for (int o = 1; o < 64; o <<= 1) {
        unsigned long long w1 = (unsigned long long)__shfl_xor((long long)m1, o);
        unsigned long long w2 = (unsigned long long)__shfl_xor((long long)m2, o);
        unsigned long long lo = umin64_(m1, w1), hi = umax64_(m1, w1);
        m1 = lo;
        m2 = umin64_(umin64_(m2, w2), hi);
    }
    const float v0 = fkey_inv((unsigned)(m1 >> 32));
    const float v1 = fkey_inv((unsigned)(m2 >> 32));

    float4 xv = ((const float4*)(x + (size_t)row * DIM))[lane];
    int tok;
    if (v1 > v0 + 1.0e-2f) {
        tok = (int)(unsigned)(m1 & 0xFFFFFFFFu);
    } else {
        // recover top-8 ids (ascending (v,id) order) by repeated extract-min
        int id8[8];
        unsigned long long cur = pk;
#pragma unroll
        for (int k = 0; k < 8; ++k) {
            unsigned long long m = cur;
#pragma unroll
            for (int o = 1; o < 64; o <<= 1)
                m = umin64_(m, (unsigned long long)__shfl_xor((long long)m, o));
            id8[k] = (int)(unsigned)(m & 0xFFFFFFFFu);
            if (cur == m) cur = ~0ull;   // owning lane removes it
        }

        double xs64 = (double)xv.x * xv.x + (double)xv.y * xv.y
                    + (double)xv.z * xv.z + (double)xv.w * xv.w;
        double dd[8], cc2[8];
#pragma unroll
        for (int k = 0; k < 8; ++k) {
            float4 c4 = ((const float4*)(cb + (size_t)id8[k] * DIM))[lane];
            dd[k]  = (double)xv.x * c4.x + (double)xv.y * c4.y
                   + (double)xv.z * c4.z + (double)xv.w * c4.w;
            cc2[k] = (double)c4.x * c4.x + (double)c4.y * c4.y
                   + (double)c4.z * c4.z + (double)c4.w * c4.w;
        }
#pragma unroll
        for (int o = 32; o; o >>= 1) {
            xs64 += __shfl_down(xs64, o);
#pragma unroll
            for (int k = 0; k < 8; ++k) {
                dd[k]  += __shfl_down(dd[k], o);
                cc2[k] += __shfl_down(cc2[k], o);
            }
        }
        if (lane == 0) {
            double D[8], Dmin = 1e300;
#pragma unroll
            for (int k = 0; k < 8; ++k) {
                D[k] = xs64 + cc2[k] - 2.0 * dd[k];
                Dmin = fmin(Dmin, D[k]);
            }
            int e2; frexp(Dmin, &e2);
            double U   = ldexp(1.0, e2 - 1 - 23);     // ulp_fp32(Dmin)
            double thr = Dmin + 0.75 * U;
            tok = 0x7FFFFFFF;
#pragma unroll
            for (int k = 0; k < 8; ++k)
                if (D[k] <= thr && id8[k] < tok) tok = id8[k];
        }
        tok = __shfl(tok, 0);
    }

    if (lane == 0) active[tok] = 1u;
    float4 sel = ((const float4*)(cb + (size_t)tok * DIM))[lane];
    ((float4*)out)[(size_t)row * 64 + lane] = sel;
    float dx = sel.x - xv.x, dy = sel.y - xv.y, dz = sel.z - xv.z, dw = sel.w - xv.w;
    float s = dx * dx + dy * dy + dz * dz + dw * dw;
    for (int o = 32; o; o >>= 1) s += __shfl_down(s, o);
    if (lane == 0) wsum[wave] = (double)s;
    __syncthreads();
    if (threadIdx.x == 0) atomicAdd(accum, wsum[0] + wsum[1] + wsum[2] + wsum[3]);
}

// ---- final: 128-way colmin reduction + entropy + loss. grid = 16 blocks.
// Each block reduces 256 codes over the 128 row-block partials, adds its
// inactive-code entropy partial; the 16th finisher computes the loss.
__global__ __launch_bounds__(256) void vq_final_kernel(
        const unsigned* __restrict__ colmin_part, const unsigned* __restrict__ active,
        double* __restrict__ accum, unsigned* __restrict__ counter,
        float* __restrict__ out) {
    __shared__ double red[256];
    const int t = threadIdx.x;
    const int c = blockIdx.x * 256 + t;
    unsigned m = 0xFFFFFFFFu;
#pragma unroll 8
    for (int rb = 0; rb < NRB; ++rb)
        m = umin_(m, colmin_part[(size_t)rb * KCODES + c]);
    red[t] = (active[c] == 0u) ? (double)fkey_inv(m) : 0.0;
    __syncthreads();
    for (int o = 128; o; o >>= 1) {
        if (t < o) red[t] += red[t + o];
        __syncthreads();
    }
    if (t == 0) {
        atomicAdd(&accum[1], red[0]);
        __threadfence();
        unsigned old = atomicAdd(counter, 1u);
        if (old == 15u) {
            __threadfence();
            double ent = atomicAdd(&accum[1], 0.0);   // atomic read
            double loss = 1.25 * (accum[0] / (double)((size_t)N_ROWS * DIM))
                        + 0.02 * (ent / (double)KCODES);
            out[(size_t)N_ROWS * DIM] = (float)loss;
        }
    }
}

extern "C" void kernel_launch(void* const* d_in, const int* in_sizes, int n_in,
                              void* d_out, int out_size, void* d_ws, size_t ws_size,
                              hipStream_t stream) {
    const float* x  = (const float*)d_in[0];   // [16384, 256]
    const float* cb = (const float*)d_in[1];   // [4096, 256]
    float* out = (float*)d_out;                // [16384*256] ++ [1] loss

    char* ws = (char*)d_ws;
    float*    xsq     = (float*)(ws + 0);                      // 64 KB
    float*    csq     = (float*)(ws + 65536);                  // 16 KB
    unsigned* active  = (unsigned*)(ws + 81920);               // 16 KB
    double*   accum   = (double*)(ws + 98304);                 // 256 B (mse, entropy)
    unsigned* counter = (unsigned*)(ws + 98560);               // 64 B
    uint2*    top2    = (uint2*)(ws + 131072);                 // 2 MB (16 granules)
    unsigned* cpart   = (unsigned*)(ws + 2228224);             // 2 MB (128 x 4096)
    unsigned short* xh_g = (unsigned short*)(ws + 4325376);    // 8 MB
    unsigned short* ch_g = (unsigned short*)(ws + 12713984);   // 2 MB (~14.2 MB)

    vq_prep_kernel<<<((N_ROWS + KCODES) * DIM) / 1024, 256, 0, stream>>>(
        x, cb, xh_g, ch_g, xsq, csq, active, accum, counter);
    vq_gemm_kernel<<<dim3(NRB, NCHUNK), 256, 0, stream>>>(
        xh_g, ch_g, xsq, csq, cpart, top2);
    vq_refine_kernel<<<N_ROWS / 4, 256, 0, stream>>>(
        x, cb, top2, active, out, accum);
    vq_final_kernel<<<KCODES / 256, 256, 0, stream>>>(
        cpart, active, accum, counter, out);
}